// Round 2
// baseline (245.090 us; speedup 1.0000x reference)
//
#include <hip/hip_runtime.h>
#include <math.h>

// B=16, N=1024, C_IN=256, C_OUT=256, POOL_RATIO=0.5
#define Bsz 16
#define Nn  1024

// d_out layout (float32): x_out[16,1024,256], adj_out[16,1024,1024], new_mask[16,1024], new_n[16]
#define ADJ_OFF    (16*1024*256)
#define MASK_OFF   (ADJ_OFF + 16*1024*1024)
#define NN_OFF     (MASK_OFF + 16*1024)

// Scratch inside adj_out region (overwritten last by k_adjout), float offsets:
#define XW_OFF_F    0                       // float[16384*256]  = 4,194,304
#define LIST_OFF_F  4194304                 // u16[16384*1024]   = 8,388,608 floats worth /2 = 4,194,304 floats... (u16 -> 2,? see below)
// lists: 16384*1024 u16 = 33,554,432 B = 8,388,608 floats -> occupies [4194304, 12582912)
#define CNT_OFF_F   12582912                // int[16384]
#define Y_OFF_F     12599296                // float[16384]
#define Z_OFF_F     12615680                // float[16384]
#define WP_OFF_F    12632064                // float[256]
#define MISC_OFF_F  12632320                // [0]=inv_norm, [1]=bias.pool
// total used 12,632,322 < 16,777,216  ✓

typedef unsigned long long u64;

// ---------------- prep: wp = W @ pool, inv_norm, bias·pool ----------------
__global__ __launch_bounds__(256) void k_prep(const float* __restrict__ W,
                                              const float* __restrict__ bias,
                                              const float* __restrict__ pool,
                                              float* __restrict__ wp,
                                              float* __restrict__ misc) {
    __shared__ float sp[256];
    __shared__ float rb[4], rq[4];
    int t = threadIdx.x;
    sp[t] = pool[t];
    __syncthreads();
    float acc = 0.f;
    const float* wr = W + t * 256;
    for (int j = 0; j < 256; j += 4) {
        float4 w4 = *(const float4*)&wr[j];
        acc = fmaf(w4.x, sp[j], acc);
        acc = fmaf(w4.y, sp[j + 1], acc);
        acc = fmaf(w4.z, sp[j + 2], acc);
        acc = fmaf(w4.w, sp[j + 3], acc);
    }
    wp[t] = acc;
    float pv = sp[t];
    float bv = bias[t] * pv;
    float qv = pv * pv;
    for (int off = 32; off > 0; off >>= 1) {
        bv += __shfl_down(bv, off, 64);
        qv += __shfl_down(qv, off, 64);
    }
    if ((t & 63) == 0) { rb[t >> 6] = bv; rq[t >> 6] = qv; }
    __syncthreads();
    if (t == 0) {
        misc[0] = 1.0f / sqrtf(rq[0] + rq[1] + rq[2] + rq[3]);
        misc[1] = rb[0] + rb[1] + rb[2] + rb[3];
    }
}

// ---------------- z = x @ wp (exact fp32 GEMV) ----------------
__global__ __launch_bounds__(256) void k_z(const float* __restrict__ x,
                                           const float* __restrict__ wp,
                                           float* __restrict__ z) {
    __shared__ float swp[256];
    int t = threadIdx.x;
    swp[t] = wp[t];
    __syncthreads();
    int wid = t >> 6, lane = t & 63;
    int row = blockIdx.x * 4 + wid;
    const float* xr = x + (size_t)row * 256;
    float acc = fmaf(xr[lane], swp[lane],
                fmaf(xr[lane + 64], swp[lane + 64],
                fmaf(xr[lane + 128], swp[lane + 128],
                     xr[lane + 192] * swp[lane + 192])));
    for (int off = 32; off > 0; off >>= 1) acc += __shfl_down(acc, off, 64);
    if (lane == 0) z[row] = acc;
}

// ---------------- xw = x @ W  (fp32 tiled GEMM, unchanged from R1) ----------------
__global__ __launch_bounds__(256) void k_xw(const float* __restrict__ X,
                                            const float* __restrict__ W,
                                            float* __restrict__ XW) {
    const int K = 256, Nc = 256;
    int bx = blockIdx.x & 3;
    int by = blockIdx.x >> 2;
    int rowBase = by * 64;
    int colBase = bx * 64;
    int tid = threadIdx.x;

    __shared__ float As[16][64];
    __shared__ float Bs[16][64];

    int m0 = (tid & 15) * 4;
    int n0 = (tid >> 4) * 4;

    float acc[4][4];
    #pragma unroll
    for (int i = 0; i < 4; ++i)
        #pragma unroll
        for (int j = 0; j < 4; ++j) acc[i][j] = 0.0f;

    int lm = tid >> 2;
    int lk = (tid & 3) * 4;
    int bk = tid >> 4;
    int bn = (tid & 15) * 4;

    for (int kt = 0; kt < K / 16; ++kt) {
        __syncthreads();
        float4 av = *(const float4*)&X[(size_t)(rowBase + lm) * K + kt * 16 + lk];
        As[lk + 0][lm] = av.x;
        As[lk + 1][lm] = av.y;
        As[lk + 2][lm] = av.z;
        As[lk + 3][lm] = av.w;
        float4 bv = *(const float4*)&W[(size_t)(kt * 16 + bk) * Nc + colBase + bn];
        *(float4*)&Bs[bk][bn] = bv;
        __syncthreads();

        #pragma unroll
        for (int kk = 0; kk < 16; ++kk) {
            float4 a = *(const float4*)&As[kk][m0];
            float4 b = *(const float4*)&Bs[kk][n0];
            float ar[4] = {a.x, a.y, a.z, a.w};
            float br[4] = {b.x, b.y, b.z, b.w};
            #pragma unroll
            for (int i = 0; i < 4; ++i)
                #pragma unroll
                for (int j = 0; j < 4; ++j)
                    acc[i][j] = fmaf(ar[i], br[j], acc[i][j]);
        }
    }

    #pragma unroll
    for (int i = 0; i < 4; ++i) {
        float4 o = make_float4(acc[i][0], acc[i][1], acc[i][2], acc[i][3]);
        *(float4*)&XW[(size_t)(rowBase + m0 + i) * Nc + colBase + n0] = o;
    }
}

// ---------------- compact adj rows -> neighbor lists; y = sum z[nbr] + b·p ----------------
__global__ __launch_bounds__(256) void k_compact_y(const float* __restrict__ adj,
                                                   const float* __restrict__ z,
                                                   const float* __restrict__ misc,
                                                   unsigned short* __restrict__ lists,
                                                   int* __restrict__ cnts,
                                                   float* __restrict__ y) {
    __shared__ int sIdx[1024];
    __shared__ int sCnt;
    __shared__ float sRed[4];
    int row = blockIdx.x, b = row >> 10, t = threadIdx.x;
    if (t == 0) sCnt = 0;
    __syncthreads();
    float4 a4 = ((const float4*)(adj + (size_t)row * 1024))[t];
    float av[4] = {a4.x, a4.y, a4.z, a4.w};
    #pragma unroll
    for (int i = 0; i < 4; ++i)
        if (av[i] != 0.0f) { int p = atomicAdd(&sCnt, 1); sIdx[p] = t * 4 + i; }
    __syncthreads();
    int cnt = sCnt;
    unsigned short* lr = lists + (size_t)row * 1024;
    for (int j = t; j < cnt; j += 256) lr[j] = (unsigned short)sIdx[j];
    // y
    const float* zb = z + (b << 10);
    float val = 0.f;
    for (int j = t; j < cnt; j += 256) val += zb[sIdx[j]];
    for (int off = 32; off > 0; off >>= 1) val += __shfl_down(val, off, 64);
    if ((t & 63) == 0) sRed[t >> 6] = val;
    __syncthreads();
    if (t == 0) {
        y[row] = sRed[0] + sRed[1] + sRed[2] + sRed[3] + misc[1];
        cnts[row] = cnt;
    }
}

// ---------------- per-batch stable ascending argsort + mask pooling ----------------
__device__ inline u64 shfl_xor_u64(u64 v, int m) {
    int lo = __shfl_xor((int)(v & 0xffffffffULL), m, 64);
    int hi = __shfl_xor((int)(v >> 32), m, 64);
    return ((u64)(unsigned)hi << 32) | (unsigned)lo;
}

__global__ __launch_bounds__(1024) void k_sortmask(const float* __restrict__ y,
                                                   const int* __restrict__ maskIn,
                                                   const int* __restrict__ nNodes,
                                                   float* __restrict__ newMask,
                                                   float* __restrict__ newN) {
    __shared__ u64 s[1024];
    __shared__ int wsum[16];
    int b = blockIdx.x, t = threadIdx.x, lane = t & 63, wid = t >> 6;
    float ky = y[(b << 10) + t];
    unsigned u = __float_as_uint(ky);
    u = (u & 0x80000000u) ? ~u : (u | 0x80000000u);   // sortable unsigned
    u64 val = ((u64)u << 32) | (unsigned)t;

    for (int k = 2; k <= 1024; k <<= 1) {
        bool up = ((t & k) == 0);
        int j = k >> 1;
        for (; j >= 64; j >>= 1) {
            s[t] = val; __syncthreads();
            u64 p = s[t ^ j]; __syncthreads();
            bool keepMin = (up == ((t & j) == 0));
            bool pLess = p < val;
            val = (keepMin == pLess) ? p : val;
        }
        for (; j >= 1; j >>= 1) {
            u64 p = shfl_xor_u64(val, j);
            bool keepMin = (up == ((t & j) == 0));
            bool pLess = p < val;
            val = (keepMin == pLess) ? p : val;
        }
    }

    int idx = (int)(val & 1023u);
    int mval = maskIn[(b << 10) + idx];
    int sc = mval;
    for (int off = 1; off < 64; off <<= 1) {
        int nv = __shfl_up(sc, off, 64);
        if (lane >= off) sc += nv;
    }
    if (lane == 63) wsum[wid] = sc;
    __syncthreads();
    int offset = 0;
    for (int w = 0; w < wid; ++w) offset += wsum[w];
    int rank = sc + offset - mval;                 // exclusive rank among masked
    int nn = nNodes[b];
    int nrem = (int)((float)nn * 0.5f);            // (1 - POOL_RATIO)
    int nm = (mval == 1 && rank < nrem) ? 0 : mval;
    newMask[(b << 10) + idx] = (float)nm;
    if (t == 0) newN[b] = (float)(nn - nrem);
}

// ---------------- x_out: gather h only for surviving rows, scale, write ----------------
__global__ __launch_bounds__(256) void k_hxout(const float* __restrict__ XW,
                                               const unsigned short* __restrict__ lists,
                                               const int* __restrict__ cnts,
                                               const float* __restrict__ y,
                                               const float* __restrict__ misc,
                                               const float* __restrict__ bias,
                                               const float* __restrict__ mf,
                                               float* __restrict__ XO) {
    __shared__ int sIdx[1024];
    int row = blockIdx.x, b = row >> 10, t = threadIdx.x;
    float* o = XO + (size_t)row * 256;
    if (mf[row] == 0.0f) { o[t] = 0.0f; return; }   // block-uniform branch
    int cnt = cnts[row];
    const unsigned short* lr = lists + (size_t)row * 1024;
    for (int j = t; j < cnt; j += 256) sIdx[j] = lr[j];
    __syncthreads();
    float acc = bias[t];
    const float* xwb = XW + (((size_t)b << 10) * 256) + t;
    int j = 0;
    for (; j + 4 <= cnt; j += 4) {
        int m0 = sIdx[j], m1 = sIdx[j + 1], m2 = sIdx[j + 2], m3 = sIdx[j + 3];
        float v0 = xwb[(size_t)m0 * 256];
        float v1 = xwb[(size_t)m1 * 256];
        float v2 = xwb[(size_t)m2 * 256];
        float v3 = xwb[(size_t)m3 * 256];
        acc += (v0 + v1) + (v2 + v3);
    }
    for (; j < cnt; ++j) acc += xwb[(size_t)sIdx[j] * 256];
    o[t] = acc * tanhf(y[row] * misc[0]);
}

// ---------------- adj_out = mf_i * adj * mf_j (streaming; also overwrites scratch) ----------------
__global__ __launch_bounds__(256) void k_adjout(const float* __restrict__ adj,
                                                const float* __restrict__ mf,
                                                float* __restrict__ AO) {
    int i = blockIdx.x * 256 + threadIdx.x;
    int b   = i >> 18;
    int rem = i & 262143;
    int r   = rem >> 8;
    int j4  = (rem & 255) << 2;
    const float* mrow = mf + b * Nn;
    float mi = mrow[r];
    float4 a4 = ((const float4*)adj)[i];
    float4 m4 = *(const float4*)&mrow[j4];
    float4 o;
    o.x = a4.x * mi * m4.x;
    o.y = a4.y * mi * m4.y;
    o.z = a4.z * mi * m4.z;
    o.w = a4.w * mi * m4.w;
    ((float4*)AO)[i] = o;
}

extern "C" void kernel_launch(void* const* d_in, const int* in_sizes, int n_in,
                              void* d_out, int out_size, void* d_ws, size_t ws_size,
                              hipStream_t stream) {
    const float* x      = (const float*)d_in[0];
    const float* adj    = (const float*)d_in[1];
    const int*   mask   = (const int*)d_in[2];
    const int*   nnodes = (const int*)d_in[3];
    const float* W      = (const float*)d_in[4];
    const float* bias   = (const float*)d_in[5];
    const float* pool   = (const float*)d_in[6];

    float* out = (float*)d_out;
    float* XO  = out;
    float* AO  = out + ADJ_OFF;
    float* NM  = out + MASK_OFF;
    float* NNo = out + NN_OFF;

    float*          XW    = AO + XW_OFF_F;
    unsigned short* LISTS = (unsigned short*)(AO + LIST_OFF_F);
    int*            CNTS  = (int*)(AO + CNT_OFF_F);
    float*          Y     = AO + Y_OFF_F;
    float*          Z     = AO + Z_OFF_F;
    float*          WP    = AO + WP_OFF_F;
    float*          MISC  = AO + MISC_OFF_F;

    k_prep<<<1, 256, 0, stream>>>(W, bias, pool, WP, MISC);
    k_z<<<Bsz * Nn / 4, 256, 0, stream>>>(x, WP, Z);
    k_xw<<<1024, 256, 0, stream>>>(x, W, XW);
    k_compact_y<<<Bsz * Nn, 256, 0, stream>>>(adj, Z, MISC, LISTS, CNTS, Y);
    k_sortmask<<<Bsz, 1024, 0, stream>>>(Y, mask, nnodes, NM, NNo);
    k_hxout<<<Bsz * Nn, 256, 0, stream>>>(XW, LISTS, CNTS, Y, MISC, bias, NM, XO);
    k_adjout<<<(Bsz * Nn * Nn / 4 + 255) / 256, 256, 0, stream>>>(adj, NM, AO);
}

// Round 3
// 208.948 us; speedup vs baseline: 1.1730x; 1.1730x over previous
//
#include <hip/hip_runtime.h>
#include <math.h>

// B=16, N=1024, C_IN=256, C_OUT=256, POOL_RATIO=0.5
#define Bsz 16
#define Nn  1024

// d_out layout (float32): x_out[16,1024,256], adj_out[16,1024,1024], new_mask[16,1024], new_n[16]
#define ADJ_OFF    (16*1024*256)
#define MASK_OFF   (ADJ_OFF + 16*1024*1024)
#define NN_OFF     (MASK_OFF + 16*1024)

typedef unsigned long long u64;
typedef unsigned short u16;
typedef short bf16x8 __attribute__((ext_vector_type(8)));
typedef float f32x4  __attribute__((ext_vector_type(4)));

// ---- manual bf16 conversions (RNE) ----
static __device__ inline u16 f2bf(float f) {
    unsigned u = __float_as_uint(f);
    u += 0x7fffu + ((u >> 16) & 1u);
    return (u16)(u >> 16);
}
static __device__ inline float bf2f(u16 h) {
    return __uint_as_float(((unsigned)h) << 16);
}

// ---------------- prep: wp = W @ pool, inv_norm, bias.pool, WT = bf16(W^T) ----------------
// blocks 0..255: WT row n = blockIdx.x ; block 256: wp/misc
__global__ __launch_bounds__(256) void k_prep(const float* __restrict__ W,
                                              const float* __restrict__ bias,
                                              const float* __restrict__ pool,
                                              float* __restrict__ wp,
                                              float* __restrict__ misc,
                                              u16* __restrict__ WT) {
    int t = threadIdx.x;
    if (blockIdx.x < 256) {
        int n = blockIdx.x;
        WT[n * 256 + t] = f2bf(W[t * 256 + n]);
        return;
    }
    __shared__ float sp[256];
    __shared__ float rb[4], rq[4];
    sp[t] = pool[t];
    __syncthreads();
    float acc = 0.f;
    const float* wr = W + t * 256;
    for (int j = 0; j < 256; j += 4) {
        float4 w4 = *(const float4*)&wr[j];
        acc = fmaf(w4.x, sp[j], acc);
        acc = fmaf(w4.y, sp[j + 1], acc);
        acc = fmaf(w4.z, sp[j + 2], acc);
        acc = fmaf(w4.w, sp[j + 3], acc);
    }
    wp[t] = acc;
    float pv = sp[t];
    float bv = bias[t] * pv;
    float qv = pv * pv;
    for (int off = 32; off > 0; off >>= 1) {
        bv += __shfl_down(bv, off, 64);
        qv += __shfl_down(qv, off, 64);
    }
    if ((t & 63) == 0) { rb[t >> 6] = bv; rq[t >> 6] = qv; }
    __syncthreads();
    if (t == 0) {
        misc[0] = 1.0f / sqrtf(rq[0] + rq[1] + rq[2] + rq[3]);
        misc[1] = rb[0] + rb[1] + rb[2] + rb[3];
    }
}

// ---------------- xcvt: XB = bf16(x), z = x @ wp (one pass over x) ----------------
__global__ __launch_bounds__(256) void k_xcvt(const float* __restrict__ x,
                                              const float* __restrict__ wp,
                                              u16* __restrict__ XB,
                                              float* __restrict__ z) {
    __shared__ float swp[256];
    int t = threadIdx.x;
    swp[t] = wp[t];
    __syncthreads();
    int wid = t >> 6, lane = t & 63;
    int row = blockIdx.x * 4 + wid;
    const float* xr = x + (size_t)row * 256;
    float4 v = ((const float4*)xr)[lane];
    const float* w4 = &swp[lane * 4];
    float acc = fmaf(v.x, w4[0], fmaf(v.y, w4[1], fmaf(v.z, w4[2], v.w * w4[3])));
    ushort4 o;
    o.x = f2bf(v.x); o.y = f2bf(v.y); o.z = f2bf(v.z); o.w = f2bf(v.w);
    ((ushort4*)(XB + (size_t)row * 256))[lane] = o;
    for (int off = 32; off > 0; off >>= 1) acc += __shfl_down(acc, off, 64);
    if (lane == 0) z[row] = acc;
}

// ---------------- XWB = XB @ WT^T  (bf16 MFMA 16x16x32, 128x128 tile, BK=64) ----------------
// A = XB [16384,256] row-major; B^T = WT [256 n][256 k] row-major; C = XWB bf16 [16384,256]
__global__ __launch_bounds__(256) void k_gemm(const u16* __restrict__ XB,
                                              const u16* __restrict__ WT,
                                              u16* __restrict__ XWB) {
    __shared__ short sA[128][72];   // [m][k], +8 pad
    __shared__ short sB[128][72];   // [n][k]
    int bm = blockIdx.x >> 1, bn = blockIdx.x & 1;
    int t = threadIdx.x, lane = t & 63, wave = t >> 6;
    int wr = (wave >> 1) * 64, wc = (wave & 1) * 64;
    int fm = lane & 15, fq = lane >> 4;

    f32x4 acc[4][4];
    #pragma unroll
    for (int i = 0; i < 4; ++i)
        #pragma unroll
        for (int j = 0; j < 4; ++j)
            acc[i][j] = (f32x4){0.f, 0.f, 0.f, 0.f};

    int sr = t >> 1, half = (t & 1) * 32;
    const u16* gA = XB + ((size_t)(bm * 128 + sr)) * 256 + half;
    const u16* gB = WT + ((size_t)(bn * 128 + sr)) * 256 + half;

    for (int kt = 0; kt < 4; ++kt) {
        __syncthreads();
        #pragma unroll
        for (int q = 0; q < 4; ++q) {
            *(int4*)&sA[sr][half + q * 8] = *(const int4*)&gA[kt * 64 + q * 8];
            *(int4*)&sB[sr][half + q * 8] = *(const int4*)&gB[kt * 64 + q * 8];
        }
        __syncthreads();
        #pragma unroll
        for (int ks = 0; ks < 64; ks += 32) {
            bf16x8 af[4], bfv[4];
            #pragma unroll
            for (int i = 0; i < 4; ++i)
                af[i] = *(const bf16x8*)&sA[wr + i * 16 + fm][ks + fq * 8];
            #pragma unroll
            for (int j = 0; j < 4; ++j)
                bfv[j] = *(const bf16x8*)&sB[wc + j * 16 + fm][ks + fq * 8];
            #pragma unroll
            for (int i = 0; i < 4; ++i)
                #pragma unroll
                for (int j = 0; j < 4; ++j)
                    acc[i][j] = __builtin_amdgcn_mfma_f32_16x16x32_bf16(af[i], bfv[j], acc[i][j], 0, 0, 0);
        }
    }
    // epilogue: C/D layout col=lane&15, row=(lane>>4)*4+reg
    #pragma unroll
    for (int i = 0; i < 4; ++i) {
        int rbase = bm * 128 + wr + i * 16 + fq * 4;
        #pragma unroll
        for (int j = 0; j < 4; ++j) {
            int c = bn * 128 + wc + j * 16 + fm;
            #pragma unroll
            for (int r = 0; r < 4; ++r)
                XWB[(size_t)(rbase + r) * 256 + c] = f2bf(acc[i][j][r]);
        }
    }
}

// ---------------- compact adj rows -> neighbor lists; y = sum z[nbr] + b.p ----------------
__global__ __launch_bounds__(256) void k_compact_y(const float* __restrict__ adj,
                                                   const float* __restrict__ z,
                                                   const float* __restrict__ misc,
                                                   u16* __restrict__ lists,
                                                   int* __restrict__ cnts,
                                                   float* __restrict__ y) {
    __shared__ int sIdx[1024];
    __shared__ int sCnt;
    __shared__ float sRed[4];
    int row = blockIdx.x, b = row >> 10, t = threadIdx.x;
    if (t == 0) sCnt = 0;
    __syncthreads();
    float4 a4 = ((const float4*)(adj + (size_t)row * 1024))[t];
    float av[4] = {a4.x, a4.y, a4.z, a4.w};
    #pragma unroll
    for (int i = 0; i < 4; ++i)
        if (av[i] != 0.0f) { int p = atomicAdd(&sCnt, 1); sIdx[p] = t * 4 + i; }
    __syncthreads();
    int cnt = sCnt;
    u16* lr = lists + (size_t)row * 1024;
    for (int j = t; j < cnt; j += 256) lr[j] = (u16)sIdx[j];
    const float* zb = z + (b << 10);
    float val = 0.f;
    for (int j = t; j < cnt; j += 256) val += zb[sIdx[j]];
    for (int off = 32; off > 0; off >>= 1) val += __shfl_down(val, off, 64);
    if ((t & 63) == 0) sRed[t >> 6] = val;
    __syncthreads();
    if (t == 0) {
        y[row] = sRed[0] + sRed[1] + sRed[2] + sRed[3] + misc[1];
        cnts[row] = cnt;
    }
}

// ---------------- per-batch stable ascending argsort + mask pooling ----------------
__device__ inline u64 shfl_xor_u64(u64 v, int m) {
    int lo = __shfl_xor((int)(v & 0xffffffffULL), m, 64);
    int hi = __shfl_xor((int)(v >> 32), m, 64);
    return ((u64)(unsigned)hi << 32) | (unsigned)lo;
}

__global__ __launch_bounds__(1024) void k_sortmask(const float* __restrict__ y,
                                                   const int* __restrict__ maskIn,
                                                   const int* __restrict__ nNodes,
                                                   float* __restrict__ newMask,
                                                   float* __restrict__ newN) {
    __shared__ u64 s[1024];
    __shared__ int wsum[16];
    int b = blockIdx.x, t = threadIdx.x, lane = t & 63, wid = t >> 6;
    float ky = y[(b << 10) + t];
    unsigned u = __float_as_uint(ky);
    u = (u & 0x80000000u) ? ~u : (u | 0x80000000u);
    u64 val = ((u64)u << 32) | (unsigned)t;

    for (int k = 2; k <= 1024; k <<= 1) {
        bool up = ((t & k) == 0);
        int j = k >> 1;
        for (; j >= 64; j >>= 1) {
            s[t] = val; __syncthreads();
            u64 p = s[t ^ j]; __syncthreads();
            bool keepMin = (up == ((t & j) == 0));
            bool pLess = p < val;
            val = (keepMin == pLess) ? p : val;
        }
        for (; j >= 1; j >>= 1) {
            u64 p = shfl_xor_u64(val, j);
            bool keepMin = (up == ((t & j) == 0));
            bool pLess = p < val;
            val = (keepMin == pLess) ? p : val;
        }
    }

    int idx = (int)(val & 1023u);
    int mval = maskIn[(b << 10) + idx];
    int sc = mval;
    for (int off = 1; off < 64; off <<= 1) {
        int nv = __shfl_up(sc, off, 64);
        if (lane >= off) sc += nv;
    }
    if (lane == 63) wsum[wid] = sc;
    __syncthreads();
    int offset = 0;
    for (int w = 0; w < wid; ++w) offset += wsum[w];
    int rank = sc + offset - mval;
    int nn = nNodes[b];
    int nrem = (int)((float)nn * 0.5f);
    int nm = (mval == 1 && rank < nrem) ? 0 : mval;
    newMask[(b << 10) + idx] = (float)nm;
    if (t == 0) newN[b] = (float)(nn - nrem);
}

// ---------------- out: x_out row (gather h) + adj_out row (zero + scatter ones) ----------------
__global__ __launch_bounds__(256) void k_out(const u16* __restrict__ XWB,
                                             const u16* __restrict__ lists,
                                             const int* __restrict__ cnts,
                                             const float* __restrict__ y,
                                             const float* __restrict__ misc,
                                             const float* __restrict__ bias,
                                             const float* __restrict__ NM,
                                             float* __restrict__ XO,
                                             float* __restrict__ AO,
                                             int doAdj) {
    __shared__ int sIdx[1024];
    int row = blockIdx.x, b = row >> 10, t = threadIdx.x;
    if (doAdj) {
        float4 z4 = make_float4(0.f, 0.f, 0.f, 0.f);
        ((float4*)(AO + (size_t)row * 1024))[t] = z4;
    }
    float mfr = NM[row];
    if (mfr == 0.0f) { XO[(size_t)row * 256 + t] = 0.0f; return; }

    int cnt = cnts[row];
    const u16* lr = lists + (size_t)row * 1024;
    for (int j = t; j < cnt; j += 256) sIdx[j] = lr[j];
    __syncthreads();   // also orders the AO zero-stores before the scatter below

    float acc = bias[t];
    const u16* xwb = XWB + (((size_t)b << 10) * 256) + t;
    int j = 0;
    for (; j + 4 <= cnt; j += 4) {
        int m0 = sIdx[j], m1 = sIdx[j + 1], m2 = sIdx[j + 2], m3 = sIdx[j + 3];
        float v0 = bf2f(xwb[(size_t)m0 * 256]);
        float v1 = bf2f(xwb[(size_t)m1 * 256]);
        float v2 = bf2f(xwb[(size_t)m2 * 256]);
        float v3 = bf2f(xwb[(size_t)m3 * 256]);
        acc += (v0 + v1) + (v2 + v3);
    }
    for (; j < cnt; ++j) acc += bf2f(xwb[(size_t)sIdx[j] * 256]);
    XO[(size_t)row * 256 + t] = acc * tanhf(y[row] * misc[0]);

    if (doAdj) {
        const float* mb = NM + (b << 10);
        for (int j2 = t; j2 < cnt; j2 += 256) {
            int c = sIdx[j2];
            if (mb[c] != 0.0f) AO[(size_t)row * 1024 + c] = 1.0f;
        }
    }
}

// ---------------- fallback dense adj_out (only if ws too small) ----------------
__global__ __launch_bounds__(256) void k_adjout_dense(const float* __restrict__ adj,
                                                      const float* __restrict__ mf,
                                                      float* __restrict__ AO) {
    int i = blockIdx.x * 256 + threadIdx.x;
    int b   = i >> 18;
    int rem = i & 262143;
    int r   = rem >> 8;
    int j4  = (rem & 255) << 2;
    const float* mrow = mf + b * Nn;
    float mi = mrow[r];
    float4 a4 = ((const float4*)adj)[i];
    float4 m4 = *(const float4*)&mrow[j4];
    float4 o;
    o.x = a4.x * mi * m4.x;
    o.y = a4.y * mi * m4.y;
    o.z = a4.z * mi * m4.z;
    o.w = a4.w * mi * m4.w;
    ((float4*)AO)[i] = o;
}

extern "C" void kernel_launch(void* const* d_in, const int* in_sizes, int n_in,
                              void* d_out, int out_size, void* d_ws, size_t ws_size,
                              hipStream_t stream) {
    const float* x      = (const float*)d_in[0];
    const float* adj    = (const float*)d_in[1];
    const int*   mask   = (const int*)d_in[2];
    const int*   nnodes = (const int*)d_in[3];
    const float* W      = (const float*)d_in[4];
    const float* bias   = (const float*)d_in[5];
    const float* pool   = (const float*)d_in[6];

    float* out = (float*)d_out;
    float* XO  = out;
    float* AO  = out + ADJ_OFF;
    float* NM  = out + MASK_OFF;
    float* NNo = out + NN_OFF;

    // scratch layout
    const size_t NEED = 50660416;
    bool useWs = (d_ws != nullptr) && (ws_size >= NEED);

    u16 *XB, *WT, *XWB, *LISTS;
    int* CNTS;
    float *Y, *Z, *WP, *MISC;
    if (useWs) {
        char* w = (char*)d_ws;
        XB    = (u16*)(w);
        WT    = (u16*)(w + 8388608);
        XWB   = (u16*)(w + 8519680);
        LISTS = (u16*)(w + 16908288);
        CNTS  = (int*)(w + 50462720);
        Y     = (float*)(w + 50528256);
        Z     = (float*)(w + 50593792);
        WP    = (float*)(w + 50659328);
        MISC  = (float*)(w + 50660352);
    } else {
        // fall back into the adj_out region (dense adjout overwrites it last)
        XWB   = (u16*)(AO);
        XB    = (u16*)(AO + 2097152);
        LISTS = (u16*)(AO + 4194304);
        CNTS  = (int*)(AO + 12582912);
        Y     = AO + 12599296;
        Z     = AO + 12615680;
        WT    = (u16*)(AO + 12632064);
        WP    = AO + 12664832;
        MISC  = AO + 12665088;
    }

    k_prep<<<257, 256, 0, stream>>>(W, bias, pool, WP, MISC, WT);
    k_xcvt<<<4096, 256, 0, stream>>>(x, WP, XB, Z);
    k_gemm<<<256, 256, 0, stream>>>(XB, WT, XWB);
    k_compact_y<<<Bsz * Nn, 256, 0, stream>>>(adj, Z, MISC, LISTS, CNTS, Y);
    k_sortmask<<<Bsz, 1024, 0, stream>>>(Y, mask, nnodes, NM, NNo);
    k_out<<<Bsz * Nn, 256, 0, stream>>>(XWB, LISTS, CNTS, Y, MISC, bias, NM, XO, AO, useWs ? 1 : 0);
    if (!useWs)
        k_adjout_dense<<<(Bsz * Nn * Nn / 4 + 255) / 256, 256, 0, stream>>>(adj, NM, AO);
}